// Round 1
// baseline (502.947 us; speedup 1.0000x reference)
//
#include <hip/hip_runtime.h>
#include <math.h>

#define Bn 16
#define Hh 512
#define Ww 512
#define TILE 16

__global__ __launch_bounds__(256) void residual_advection_fused(
    const float* __restrict__ pm25,   // (16,1,512,512)
    const float* __restrict__ wind,   // (16,2,512,512)
    const float* __restrict__ topo,   // (16,1,512,512)
    const float* __restrict__ w1,     // (16,3,3,3)
    const float* __restrict__ b1,     // (16)
    const float* __restrict__ w2,     // (18,16,3,3)
    const float* __restrict__ b2,     // (18)
    const float* __restrict__ wt,     // (9)
    float* __restrict__ out)          // (16,1,512,512)
{
    __shared__ float s_in[3][20][20];     // input halo (origin ty0-2, tx0-2)
    __shared__ float s_feat[16][18][18];  // gelu(conv1) halo (origin ty0-1, tx0-1)

    const int tid = threadIdx.x;
    const int bb  = blockIdx.z;
    const int ty0 = blockIdx.y * TILE;
    const int tx0 = blockIdx.x * TILE;
    const int HW  = Hh * Ww;

    // ---- stage input halo (zero outside image = conv1 zero padding) ----
    for (int idx = tid; idx < 3 * 20 * 20; idx += 256) {
        int c   = idx / 400;
        int rem = idx - c * 400;
        int ly  = rem / 20;
        int lx  = rem - ly * 20;
        int gy  = ty0 - 2 + ly;
        int gx  = tx0 - 2 + lx;
        float v = 0.0f;
        if (gy >= 0 && gy < Hh && gx >= 0 && gx < Ww) {
            if (c < 2) v = wind[(bb * 2 + c) * HW + gy * Ww + gx];
            else       v = topo[bb * HW + gy * Ww + gx];
        }
        s_in[c][ly][lx] = v;
    }
    __syncthreads();

    // ---- conv1 + exact GELU into feat halo (zero outside image = conv2 zero padding) ----
    for (int pos = tid; pos < 18 * 18; pos += 256) {
        int ly = pos / 18;
        int lx = pos - ly * 18;
        int gy = ty0 - 1 + ly;
        int gx = tx0 - 1 + lx;
        if (gy < 0 || gy >= Hh || gx < 0 || gx >= Ww) {
            #pragma unroll
            for (int co = 0; co < 16; ++co) s_feat[co][ly][lx] = 0.0f;
        } else {
            float f[27];
            #pragma unroll
            for (int ci = 0; ci < 3; ++ci)
                #pragma unroll
                for (int ky = 0; ky < 3; ++ky)
                    #pragma unroll
                    for (int kx = 0; kx < 3; ++kx)
                        f[ci * 9 + ky * 3 + kx] = s_in[ci][ly + ky][lx + kx];
            #pragma unroll
            for (int co = 0; co < 16; ++co) {
                float s = b1[co];
                #pragma unroll
                for (int j = 0; j < 27; ++j) s += f[j] * w1[co * 27 + j];
                // exact gelu: 0.5*x*(1+erf(x/sqrt(2)))
                float g = 0.5f * s * (1.0f + erff(s * 0.70710678118654752f));
                s_feat[co][ly][lx] = g;
            }
        }
    }
    __syncthreads();

    // ---- conv2 (K=144 dot product per output pixel, 18 output channels) ----
    const int ty = tid >> 4;
    const int tx = tid & 15;

    float acc[18];
    #pragma unroll
    for (int co = 0; co < 18; ++co) acc[co] = b2[co];

    for (int ci = 0; ci < 16; ++ci) {
        float f[9];
        #pragma unroll
        for (int ky = 0; ky < 3; ++ky)
            #pragma unroll
            for (int kx = 0; kx < 3; ++kx)
                f[ky * 3 + kx] = s_feat[ci][ty + ky][tx + kx];
        #pragma unroll
        for (int co = 0; co < 18; ++co) {
            float a = acc[co];
            #pragma unroll
            for (int j = 0; j < 9; ++j) a += f[j] * w2[(co * 16 + ci) * 9 + j];
            acc[co] = a;
        }
    }

    // ---- deformable 3x3 bilinear sampling of pm25, weighted by wt ----
    const int y = ty0 + ty;
    const int x = tx0 + tx;
    const float* img = pm25 + bb * HW;

    float o = 0.0f;
    #pragma unroll
    for (int k = 0; k < 9; ++k) {
        float wk = wt[k];               // wave-uniform
        if (wk != 0.0f) {               // uniform branch: skips zero taps
            float dy = acc[2 * k];
            float dx = acc[2 * k + 1];
            float py = (float)y + (float)(k / 3 - 1) + dy;
            float px = (float)x + (float)(k % 3 - 1) + dx;
            float y0f = floorf(py), x0f = floorf(px);
            float wy = py - y0f, wx = px - x0f;
            int y0 = (int)y0f, x0 = (int)x0f;

            auto corner = [&](int yi, int xi) -> float {
                bool valid = (yi >= 0) && (yi < Hh) && (xi >= 0) && (xi < Ww);
                int yc = min(max(yi, 0), Hh - 1);
                int xc = min(max(xi, 0), Ww - 1);
                float v = img[yc * Ww + xc];
                return valid ? v : 0.0f;
            };

            float v00 = corner(y0,     x0);
            float v01 = corner(y0,     x0 + 1);
            float v10 = corner(y0 + 1, x0);
            float v11 = corner(y0 + 1, x0 + 1);

            o += wk * ((1.0f - wy) * ((1.0f - wx) * v00 + wx * v01) +
                       wy          * ((1.0f - wx) * v10 + wx * v11));
        }
    }
    out[bb * HW + y * Ww + x] = o;
}

extern "C" void kernel_launch(void* const* d_in, const int* in_sizes, int n_in,
                              void* d_out, int out_size, void* d_ws, size_t ws_size,
                              hipStream_t stream) {
    const float* pm25 = (const float*)d_in[0];
    const float* wind = (const float*)d_in[1];
    const float* topo = (const float*)d_in[2];
    const float* w1   = (const float*)d_in[3];
    const float* b1   = (const float*)d_in[4];
    const float* w2   = (const float*)d_in[5];
    const float* b2   = (const float*)d_in[6];
    const float* wt   = (const float*)d_in[7];
    float* o          = (float*)d_out;

    dim3 grid(Ww / TILE, Hh / TILE, Bn);
    residual_advection_fused<<<grid, dim3(256), 0, stream>>>(
        pm25, wind, topo, w1, b1, w2, b2, wt, o);
}

// Round 2
// 484.960 us; speedup vs baseline: 1.0371x; 1.0371x over previous
//
#include <hip/hip_runtime.h>
#include <math.h>

#define Bn 16
#define Hh 512
#define Ww 512
#define TILE 16

typedef __bf16 bfrag  __attribute__((ext_vector_type(8)));
typedef float  ffrag  __attribute__((ext_vector_type(16)));

__device__ __forceinline__ short f2bf(float f) {           // RNE fp32 -> bf16 bits
    unsigned u = __float_as_uint(f);
    unsigned r = u + 0x7FFFu + ((u >> 16) & 1u);
    return (short)(r >> 16);
}
__device__ __forceinline__ float bf2f(short s) {
    return __uint_as_float(((unsigned)(unsigned short)s) << 16);
}

// LDS layout (bytes):
//   [0, 4800)        s_in    : float [3][20][20]
//   [4800, 15168)    s_feat_h: bf16  [324][16]   (halo pos major, ci inner)
//   [15168, 25536)   s_feat_l: bf16  [324][16]
//   [4800, 24256)    s_off   : float [256][19]   (ALIASES feat; used after sync)
#define SMEM_BYTES 25536

__global__ __launch_bounds__(256, 4) void residual_advection_fused(
    const float* __restrict__ pm25,   // (16,1,512,512)
    const float* __restrict__ wind,   // (16,2,512,512)
    const float* __restrict__ topo,   // (16,1,512,512)
    const float* __restrict__ w1,     // (16,3,3,3)
    const float* __restrict__ b1,     // (16)
    const float* __restrict__ w2,     // (18,16,3,3)
    const float* __restrict__ b2,     // (18)
    const float* __restrict__ wt,     // (9)
    float* __restrict__ out)          // (16,1,512,512)
{
    __shared__ __align__(16) char smem[SMEM_BYTES];
    float (*s_in)[20][20] = (float (*)[20][20])smem;
    __bf16* s_feat_h = (__bf16*)(smem + 4800);
    __bf16* s_feat_l = (__bf16*)(smem + 15168);
    float*  s_off    = (float*)(smem + 4800);

    const int tid = threadIdx.x;
    const int bb  = blockIdx.z;
    const int ty0 = blockIdx.y * TILE;
    const int tx0 = blockIdx.x * TILE;
    const int HW  = Hh * Ww;

    // ---- stage input halo (zero outside image = conv1 zero padding) ----
    for (int idx = tid; idx < 3 * 20 * 20; idx += 256) {
        int c   = idx / 400;
        int rem = idx - c * 400;
        int ly  = rem / 20;
        int lx  = rem - ly * 20;
        int gy  = ty0 - 2 + ly;
        int gx  = tx0 - 2 + lx;
        float v = 0.0f;
        if (gy >= 0 && gy < Hh && gx >= 0 && gx < Ww) {
            if (c < 2) v = wind[(bb * 2 + c) * HW + gy * Ww + gx];
            else       v = topo[bb * HW + gy * Ww + gx];
        }
        s_in[c][ly][lx] = v;
    }
    __syncthreads();

    // ---- conv1 + exact GELU -> bf16 hi/lo split feat halo in LDS ----
    for (int pos = tid; pos < 18 * 18; pos += 256) {
        int ly = pos / 18;
        int lx = pos - ly * 18;
        int gy = ty0 - 1 + ly;
        int gx = tx0 - 1 + lx;
        float gv[16];
        if (gy < 0 || gy >= Hh || gx < 0 || gx >= Ww) {
            #pragma unroll
            for (int co = 0; co < 16; ++co) gv[co] = 0.0f;
        } else {
            float f[27];
            #pragma unroll
            for (int ci = 0; ci < 3; ++ci)
                #pragma unroll
                for (int ky = 0; ky < 3; ++ky)
                    #pragma unroll
                    for (int kx = 0; kx < 3; ++kx)
                        f[ci * 9 + ky * 3 + kx] = s_in[ci][ly + ky][lx + kx];
            #pragma unroll
            for (int co = 0; co < 16; ++co) {
                float s = b1[co];
                #pragma unroll
                for (int j = 0; j < 27; ++j) s += f[j] * w1[co * 27 + j];
                gv[co] = 0.5f * s * (1.0f + erff(s * 0.70710678118654752f));
            }
        }
        int hp[8], lp[8];
        #pragma unroll
        for (int j = 0; j < 8; ++j) {
            float v0 = gv[2 * j], v1 = gv[2 * j + 1];
            short h0 = f2bf(v0), h1 = f2bf(v1);
            short l0 = f2bf(v0 - bf2f(h0)), l1 = f2bf(v1 - bf2f(h1));
            hp[j] = ((int)(unsigned short)h0) | ((int)h1 << 16);
            lp[j] = ((int)(unsigned short)l0) | ((int)l1 << 16);
        }
        int4* dh = (int4*)&s_feat_h[pos * 16];
        dh[0] = make_int4(hp[0], hp[1], hp[2], hp[3]);
        dh[1] = make_int4(hp[4], hp[5], hp[6], hp[7]);
        int4* dl = (int4*)&s_feat_l[pos * 16];
        dl[0] = make_int4(lp[0], lp[1], lp[2], lp[3]);
        dl[1] = make_int4(lp[4], lp[5], lp[6], lp[7]);
    }
    __syncthreads();

    // ---- conv2 via MFMA 32x32x16 bf16, hi/lo split (3 MFMAs per product) ----
    // M = 256 pixels (per-wave: 2 m-tiles of 32), N = 18 co (pad to 32),
    // K = 16 ci per tap, 9 taps.
    const int lane = tid & 63;
    const int wv   = tid >> 6;
    const int l31  = lane & 31;
    const int lh   = lane >> 5;     // which K-half (8 ci) this lane holds

    const int m0   = wv * 64 + l31;        // m-tile 0 pixel
    const int m1   = m0 + 32;              // m-tile 1 pixel
    const int tyA0 = m0 >> 4, txA0 = m0 & 15;
    const int tyA1 = m1 >> 4, txA1 = m1 & 15;

    ffrag acc0, acc1;
    #pragma unroll
    for (int r = 0; r < 16; ++r) { acc0[r] = 0.0f; acc1[r] = 0.0f; }

    #pragma unroll
    for (int tap = 0; tap < 9; ++tap) {
        const int ky = tap / 3;
        const int kx = tap - ky * 3;

        // B fragment: B[k=ci][n=co], lane holds n=l31, k = lh*8 + j
        union { int4 i; bfrag b; } ubh, ubl;
        if (l31 < 18) {
            int hp[4], lp[4];
            #pragma unroll
            for (int jj = 0; jj < 4; ++jj) {
                float v0 = w2[(l31 * 16 + lh * 8 + 2 * jj    ) * 9 + tap];
                float v1 = w2[(l31 * 16 + lh * 8 + 2 * jj + 1) * 9 + tap];
                short h0 = f2bf(v0), h1 = f2bf(v1);
                short l0 = f2bf(v0 - bf2f(h0)), l1 = f2bf(v1 - bf2f(h1));
                hp[jj] = ((int)(unsigned short)h0) | ((int)h1 << 16);
                lp[jj] = ((int)(unsigned short)l0) | ((int)l1 << 16);
            }
            ubh.i = make_int4(hp[0], hp[1], hp[2], hp[3]);
            ubl.i = make_int4(lp[0], lp[1], lp[2], lp[3]);
        } else {
            ubh.i = make_int4(0, 0, 0, 0);
            ubl.i = make_int4(0, 0, 0, 0);
        }

        // A fragments: A[m][k] = feat[(tyA+ky)*18 + (txA+kx)][ci = lh*8 + j]
        const int idx0 = ((tyA0 + ky) * 18 + (txA0 + kx)) * 16 + lh * 8;
        const int idx1 = ((tyA1 + ky) * 18 + (txA1 + kx)) * 16 + lh * 8;
        bfrag a0h = *(const bfrag*)&s_feat_h[idx0];
        bfrag a0l = *(const bfrag*)&s_feat_l[idx0];
        bfrag a1h = *(const bfrag*)&s_feat_h[idx1];
        bfrag a1l = *(const bfrag*)&s_feat_l[idx1];

        acc0 = __builtin_amdgcn_mfma_f32_32x32x16_bf16(a0h, ubh.b, acc0, 0, 0, 0);
        acc0 = __builtin_amdgcn_mfma_f32_32x32x16_bf16(a0l, ubh.b, acc0, 0, 0, 0);
        acc0 = __builtin_amdgcn_mfma_f32_32x32x16_bf16(a0h, ubl.b, acc0, 0, 0, 0);
        acc1 = __builtin_amdgcn_mfma_f32_32x32x16_bf16(a1h, ubh.b, acc1, 0, 0, 0);
        acc1 = __builtin_amdgcn_mfma_f32_32x32x16_bf16(a1l, ubh.b, acc1, 0, 0, 0);
        acc1 = __builtin_amdgcn_mfma_f32_32x32x16_bf16(a1h, ubl.b, acc1, 0, 0, 0);
    }

    __syncthreads();   // all waves done with s_feat before s_off overwrites it

    // ---- write D (+bias) to s_off[m][co] (stride 19 to dodge conflicts) ----
    // C/D layout: col(co) = lane&31, row = (reg&3) + 8*(reg>>2) + 4*(lane>>5)
    if (l31 < 18) {
        float bias = b2[l31];
        #pragma unroll
        for (int reg = 0; reg < 16; ++reg) {
            int row = (reg & 3) + 8 * (reg >> 2) + 4 * lh;
            s_off[(wv * 64 + row) * 19 + l31]      = acc0[reg] + bias;
            s_off[(wv * 64 + 32 + row) * 19 + l31] = acc1[reg] + bias;
        }
    }
    __syncthreads();

    // ---- deformable 3x3 bilinear sampling of pm25, weighted by wt ----
    const int ty = tid >> 4;
    const int tx = tid & 15;
    const int y  = ty0 + ty;
    const int x  = tx0 + tx;
    const float* img  = pm25 + bb * HW;
    const float* offp = s_off + tid * 19;

    float o = 0.0f;
    #pragma unroll
    for (int k = 0; k < 9; ++k) {
        float wk = wt[k];               // wave-uniform
        if (wk != 0.0f) {               // uniform branch: skips zero taps
            float dy = offp[2 * k];
            float dx = offp[2 * k + 1];
            float py = (float)y + (float)(k / 3 - 1) + dy;
            float px = (float)x + (float)(k % 3 - 1) + dx;
            float y0f = floorf(py), x0f = floorf(px);
            float wy = py - y0f, wx = px - x0f;
            int y0 = (int)y0f, x0 = (int)x0f;

            auto corner = [&](int yi, int xi) -> float {
                bool valid = (yi >= 0) && (yi < Hh) && (xi >= 0) && (xi < Ww);
                int yc = min(max(yi, 0), Hh - 1);
                int xc = min(max(xi, 0), Ww - 1);
                float v = img[yc * Ww + xc];
                return valid ? v : 0.0f;
            };

            float v00 = corner(y0,     x0);
            float v01 = corner(y0,     x0 + 1);
            float v10 = corner(y0 + 1, x0);
            float v11 = corner(y0 + 1, x0 + 1);

            o += wk * ((1.0f - wy) * ((1.0f - wx) * v00 + wx * v01) +
                       wy          * ((1.0f - wx) * v10 + wx * v11));
        }
    }
    out[bb * HW + y * Ww + x] = o;
}

extern "C" void kernel_launch(void* const* d_in, const int* in_sizes, int n_in,
                              void* d_out, int out_size, void* d_ws, size_t ws_size,
                              hipStream_t stream) {
    const float* pm25 = (const float*)d_in[0];
    const float* wind = (const float*)d_in[1];
    const float* topo = (const float*)d_in[2];
    const float* w1   = (const float*)d_in[3];
    const float* b1   = (const float*)d_in[4];
    const float* w2   = (const float*)d_in[5];
    const float* b2   = (const float*)d_in[6];
    const float* wt   = (const float*)d_in[7];
    float* o          = (float*)d_out;

    dim3 grid(Ww / TILE, Hh / TILE, Bn);
    residual_advection_fused<<<grid, dim3(256), 0, stream>>>(
        pm25, wind, topo, w1, b1, w2, b2, wt, o);
}

// Round 3
// 316.168 us; speedup vs baseline: 1.5908x; 1.5339x over previous
//
#include <hip/hip_runtime.h>
#include <math.h>

#define Bn 16
#define Hh 512
#define Ww 512
#define TILE 16
#define NTHREADS 384

typedef __bf16 bfrag  __attribute__((ext_vector_type(8)));
typedef float  ffrag  __attribute__((ext_vector_type(16)));

__device__ __forceinline__ short f2bf(float f) {           // RNE fp32 -> bf16 bits
    unsigned u = __float_as_uint(f);
    unsigned r = u + 0x7FFFu + ((u >> 16) & 1u);
    return (short)(r >> 16);
}

// exact-GELU via A&S 7.1.26 erf approx (|eps| <= 1.5e-7), ~14 VALU inst
__device__ __forceinline__ float gelu_fast(float s) {
    float u  = s * 0.70710678118654752f;
    float au = fabsf(u);
    float t  = __builtin_amdgcn_rcpf(fmaf(0.3275911f, au, 1.0f));
    float p  = t * fmaf(t, fmaf(t, fmaf(t, fmaf(t, 1.061405429f, -1.453152027f),
                                        1.421413741f), -0.284496736f), 0.254829592f);
    float e  = __builtin_amdgcn_exp2f(-u * u * 1.44269504088896340f);
    float er = fmaf(-p, e, 1.0f);            // erf(|u|)
    er = copysignf(er, u);
    return 0.5f * s * (1.0f + er);
}

// ---- pre-pass: pack w2 into bf16 MFMA B-fragments in d_ws ----
// layout: [tap][lane] -> 8 bf16 (16 B). B[k=ci][n=co]: lane n=l31, k=lh*8+j.
__global__ void pack_w2(const float* __restrict__ w2, int* __restrict__ ws) {
    const int lane = threadIdx.x;            // 64 threads
    const int l31  = lane & 31;
    const int lh   = lane >> 5;
    for (int tap = 0; tap < 9; ++tap) {
        int pk[4];
        #pragma unroll
        for (int jj = 0; jj < 4; ++jj) {
            float v0 = (l31 < 18) ? w2[(l31 * 16 + lh * 8 + 2 * jj    ) * 9 + tap] : 0.0f;
            float v1 = (l31 < 18) ? w2[(l31 * 16 + lh * 8 + 2 * jj + 1) * 9 + tap] : 0.0f;
            pk[jj] = ((int)(unsigned short)f2bf(v0)) | ((int)f2bf(v1) << 16);
        }
        ((int4*)ws)[tap * 64 + lane] = make_int4(pk[0], pk[1], pk[2], pk[3]);
    }
}

// LDS layout (bytes):
//   [0, 4800)        s_in   : float [3][20][20]
//   [4800, 15168)    s_feat : bf16  [2][324][8]   ([k-half][halo pos][8 ci])
//   [4800, 24256)    s_off  : float [256][19]     (ALIASES feat; used after sync)
#define SMEM_BYTES 24256

__global__ __launch_bounds__(NTHREADS) void residual_advection_fused(
    const float* __restrict__ pm25,   // (16,1,512,512)
    const float* __restrict__ wind,   // (16,2,512,512)
    const float* __restrict__ topo,   // (16,1,512,512)
    const float* __restrict__ w1,     // (16,3,3,3)
    const float* __restrict__ b1,     // (16)
    const float* __restrict__ b2,     // (18)
    const float* __restrict__ wt,     // (9)
    const int*   __restrict__ wsB,    // packed w2 B-fragments
    float* __restrict__ out)          // (16,1,512,512)
{
    __shared__ __align__(16) char smem[SMEM_BYTES];
    float (*s_in)[20][20] = (float (*)[20][20])smem;
    __bf16* s_feat = (__bf16*)(smem + 4800);   // [2][324][8]
    float*  s_off  = (float*)(smem + 4800);    // [256][19]

    const int tid = threadIdx.x;
    const int bb  = blockIdx.z;
    const int ty0 = blockIdx.y * TILE;
    const int tx0 = blockIdx.x * TILE;
    const int HW  = Hh * Ww;

    // ---- stage input halo (zero outside image = conv1 zero padding) ----
    for (int idx = tid; idx < 3 * 20 * 20; idx += NTHREADS) {
        int c   = idx / 400;
        int rem = idx - c * 400;
        int ly  = rem / 20;
        int lx  = rem - ly * 20;
        int gy  = ty0 - 2 + ly;
        int gx  = tx0 - 2 + lx;
        float v = 0.0f;
        if (gy >= 0 && gy < Hh && gx >= 0 && gx < Ww) {
            if (c < 2) v = wind[(bb * 2 + c) * HW + gy * Ww + gx];
            else       v = topo[bb * HW + gy * Ww + gx];
        }
        s_in[c][ly][lx] = v;
    }
    __syncthreads();

    // ---- conv1 + fast exact GELU -> bf16 feat halo (single pass, 324<=384) ----
    if (tid < 18 * 18) {
        int ly = tid / 18;
        int lx = tid - ly * 18;
        int gy = ty0 - 1 + ly;
        int gx = tx0 - 1 + lx;
        float gv[16];
        if (gy < 0 || gy >= Hh || gx < 0 || gx >= Ww) {
            #pragma unroll
            for (int co = 0; co < 16; ++co) gv[co] = 0.0f;
        } else {
            float f[27];
            #pragma unroll
            for (int ci = 0; ci < 3; ++ci)
                #pragma unroll
                for (int ky = 0; ky < 3; ++ky)
                    #pragma unroll
                    for (int kx = 0; kx < 3; ++kx)
                        f[ci * 9 + ky * 3 + kx] = s_in[ci][ly + ky][lx + kx];
            #pragma unroll
            for (int co = 0; co < 16; ++co) {
                float s = b1[co];
                #pragma unroll
                for (int j = 0; j < 27; ++j) s += f[j] * w1[co * 27 + j];
                gv[co] = gelu_fast(s);
            }
        }
        #pragma unroll
        for (int half = 0; half < 2; ++half) {
            int pk[4];
            #pragma unroll
            for (int jj = 0; jj < 4; ++jj) {
                pk[jj] = ((int)(unsigned short)f2bf(gv[half * 8 + 2 * jj]))
                       | ((int)f2bf(gv[half * 8 + 2 * jj + 1]) << 16);
            }
            *(int4*)&s_feat[(half * 324 + tid) * 8] = make_int4(pk[0], pk[1], pk[2], pk[3]);
        }
    }
    __syncthreads();

    // ---- conv2 via MFMA 32x32x16 bf16 (waves 0-3; M=256 px, N=18 co, K=16x9) ----
    const int lane = tid & 63;
    const int wv   = tid >> 6;
    const int l31  = lane & 31;
    const int lh   = lane >> 5;

    ffrag acc0, acc1;
    #pragma unroll
    for (int r = 0; r < 16; ++r) { acc0[r] = 0.0f; acc1[r] = 0.0f; }

    if (wv < 4) {
        const int m0   = wv * 64 + l31;
        const int m1   = m0 + 32;
        const int tyA0 = m0 >> 4, txA0 = m0 & 15;
        const int tyA1 = m1 >> 4, txA1 = m1 & 15;
        const bfrag* Bf = (const bfrag*)wsB;

        #pragma unroll
        for (int tap = 0; tap < 9; ++tap) {
            const int ky = tap / 3;
            const int kx = tap - ky * 3;
            bfrag b = Bf[tap * 64 + lane];
            const int p0 = (tyA0 + ky) * 18 + (txA0 + kx);
            const int p1 = (tyA1 + ky) * 18 + (txA1 + kx);
            bfrag a0 = *(const bfrag*)&s_feat[(lh * 324 + p0) * 8];
            bfrag a1 = *(const bfrag*)&s_feat[(lh * 324 + p1) * 8];
            acc0 = __builtin_amdgcn_mfma_f32_32x32x16_bf16(a0, b, acc0, 0, 0, 0);
            acc1 = __builtin_amdgcn_mfma_f32_32x32x16_bf16(a1, b, acc1, 0, 0, 0);
        }
    }
    __syncthreads();   // all reads of s_feat done before s_off overwrites

    // ---- write D (+bias) to s_off[m][co] (stride 19) ----
    // C/D layout: col(co) = lane&31, row = (reg&3) + 8*(reg>>2) + 4*(lane>>5)
    if (wv < 4 && l31 < 18) {
        float bias = b2[l31];
        #pragma unroll
        for (int reg = 0; reg < 16; ++reg) {
            int row = (reg & 3) + 8 * (reg >> 2) + 4 * lh;
            s_off[(wv * 64 + row) * 19 + l31]      = acc0[reg] + bias;
            s_off[(wv * 64 + 32 + row) * 19 + l31] = acc1[reg] + bias;
        }
    }
    __syncthreads();

    // ---- deformable 3x3 bilinear sampling of pm25, weighted by wt ----
    if (tid < 256) {
        const int ty = tid >> 4;
        const int tx = tid & 15;
        const int y  = ty0 + ty;
        const int x  = tx0 + tx;
        const float* img  = pm25 + bb * HW;
        const float* offp = s_off + tid * 19;

        float o = 0.0f;
        #pragma unroll
        for (int k = 0; k < 9; ++k) {
            float wk = wt[k];               // wave-uniform
            if (wk != 0.0f) {               // uniform branch: skips zero taps
                float dy = offp[2 * k];
                float dx = offp[2 * k + 1];
                float py = (float)y + (float)(k / 3 - 1) + dy;
                float px = (float)x + (float)(k % 3 - 1) + dx;
                float y0f = floorf(py), x0f = floorf(px);
                float wy = py - y0f, wx = px - x0f;
                int y0 = (int)y0f, x0 = (int)x0f;

                auto corner = [&](int yi, int xi) -> float {
                    bool valid = (yi >= 0) && (yi < Hh) && (xi >= 0) && (xi < Ww);
                    int yc = min(max(yi, 0), Hh - 1);
                    int xc = min(max(xi, 0), Ww - 1);
                    float v = img[yc * Ww + xc];
                    return valid ? v : 0.0f;
                };

                float v00 = corner(y0,     x0);
                float v01 = corner(y0,     x0 + 1);
                float v10 = corner(y0 + 1, x0);
                float v11 = corner(y0 + 1, x0 + 1);

                o += wk * ((1.0f - wy) * ((1.0f - wx) * v00 + wx * v01) +
                           wy          * ((1.0f - wx) * v10 + wx * v11));
            }
        }
        out[bb * HW + y * Ww + x] = o;
    }
}

extern "C" void kernel_launch(void* const* d_in, const int* in_sizes, int n_in,
                              void* d_out, int out_size, void* d_ws, size_t ws_size,
                              hipStream_t stream) {
    const float* pm25 = (const float*)d_in[0];
    const float* wind = (const float*)d_in[1];
    const float* topo = (const float*)d_in[2];
    const float* w1   = (const float*)d_in[3];
    const float* b1   = (const float*)d_in[4];
    const float* w2   = (const float*)d_in[5];
    const float* b2   = (const float*)d_in[6];
    const float* wt   = (const float*)d_in[7];
    float* o          = (float*)d_out;
    int*   wsB        = (int*)d_ws;   // 9*64*16 = 9216 bytes

    pack_w2<<<dim3(1), dim3(64), 0, stream>>>(w2, wsB);

    dim3 grid(Ww / TILE, Hh / TILE, Bn);
    residual_advection_fused<<<grid, dim3(NTHREADS), 0, stream>>>(
        pm25, wind, topo, w1, b1, b2, wt, wsB, o);
}